// Round 11
// baseline (713.248 us; speedup 1.0000x reference)
//
#include <hip/hip_runtime.h>

#define HID   15
#define TMAIN 1024
#define FUT   64
#define OUTW  (TMAIN + FUT)   // 1088

typedef _Float16 v2h __attribute__((ext_vector_type(2)));
typedef _Float16 v8h __attribute__((ext_vector_type(8)));
typedef float    v4f __attribute__((ext_vector_type(4)));
typedef int      v4i __attribute__((ext_vector_type(4)));

__device__ __forceinline__ float rcp_(float x)  { return __builtin_amdgcn_rcpf(x); }
__device__ __forceinline__ float exp2_(float x) { return __builtin_amdgcn_exp2f(x); }
__device__ __forceinline__ float tanh_(float x) {
    return __builtin_fmaf(2.0f, rcp_(1.0f + exp2_(x * -2.885390081777927f)), -1.0f);
}

template<int I> struct ic { static constexpr int v = I; };
template<int J, int N, class F>
__device__ __forceinline__ void unroll_for(F&& f) {
    if constexpr (J < N) { f(ic<J>{}); unroll_for<J + 1, N>(f); }
}

// DPP ctrl: 0x150+j = row_newbcast:j (CDNA), 0x110+n = row_shr:n, 0x101 = row_shl:1
template<int CTRL>
__device__ __forceinline__ int dppi(int x) {
    return __builtin_amdgcn_update_dpp(0, x, CTRL, 0xF, 0xF, true);
}
template<int CTRL>
__device__ __forceinline__ float dppf(float x) {
    return __int_as_float(dppi<CTRL>(__float_as_int(x)));
}
__device__ __forceinline__ float row_sum_bcast(float p) {
    p += dppf<0x111>(p);
    p += dppf<0x112>(p);
    p += dppf<0x114>(p);
    p += dppf<0x118>(p);
    return dppf<0x15F>(p);
}
__device__ __forceinline__ int bperm(int addr, int src) {
    return __builtin_amdgcn_ds_bpermute(addr, src);
}
__device__ __forceinline__ v4f mfma16x32(v8h a, v8h b, v4f c) {
    return __builtin_amdgcn_mfma_f32_16x16x32_f16(a, b, c, 0, 0, 0);
}

// R11: MACs -> MFMA pipe (v_mfma_f32_16x16x32_f16), acts stay in the n=4 VALU
// layout (lane = g*16+k, g = batch, k = unit). 1024 waves preserved (trans
// throughput needs every SIMD hosting a wave). MFMA layouts (HW-verified in
// guide): A[m=lane&15][kd=(lane>>4)*8+j]; B[kd=(lane>>4)*8+j][n=lane&15];
// C/D row=(lane>>4)*4+reg, col=lane&15. Batches occupy cols/rows 0..3; unused
// N-columns waste MFMA throughput (fine: 8 MFMA/step vs idle pipe).
//  - L1: D1_gi = A1_gi (W_hh1 rows gi*15.., bias in col kd=15) x B1([h1;1]).
//  - L2 fused K=32: A2 = [W_ih2 | bias | W_hh2], B2 = [h1(t);1;h2(t-1)].
//  - B-frags built from the packed fp16 h pairs by ds_bpermute transpose
//    (addresses lane-constant). B1(t+1) = h1-half of B2(t) (4 cndmask, free).
//  - D->act redistribution: 4 bpermutes (one per D reg, same lane-const addr)
//    + lane-const selects. x term: post-redist fma with row_newbcast x.
__global__ __launch_bounds__(256)
__attribute__((amdgpu_waves_per_eu(1, 1)))
void lstm_seq_kernel(const float* __restrict__ input,
                     const float* __restrict__ W_ih1, const float* __restrict__ W_hh1,
                     const float* __restrict__ b_ih1, const float* __restrict__ b_hh1,
                     const float* __restrict__ W_ih2, const float* __restrict__ W_hh2,
                     const float* __restrict__ b_ih2, const float* __restrict__ b_hh2,
                     const float* __restrict__ W_lin, const float* __restrict__ b_lin,
                     float* __restrict__ out)
{
    const int tid  = threadIdx.x;
    const int wq   = tid >> 6;
    const int lane = tid & 63;
    const int g    = lane >> 4;       // batch row (act layout) == MFMA quad
    const int k    = lane & 15;       // unit (act layout) == MFMA m/n index
    const int b0   = (blockIdx.x * 4 + wq) * 4;

    const bool pad = (k >= HID);
    const int  kk  = pad ? 0 : k;
    const float m  = pad ? 0.0f : 1.0f;

    const float L2E = 1.442695040888963f;
    const float sA[4] = {-L2E, -L2E, -2.0f * L2E, -L2E};  // i,f sigm; g tanh; o sigm

    // ---- A-fragments (f16, scales folded). Row m=15 zeroed -> pad unit h==0.
    v8h A1[4], A2[4];
    #pragma unroll
    for (int gi = 0; gi < 4; ++gi) {
        const int row = gi * HID + kk;
        const float s = m * sA[gi];
        #pragma unroll
        for (int j = 0; j < 8; ++j) {
            const int kd = g * 8 + j;
            float a1 = 0.0f, a2 = 0.0f;
            if (kd < HID) {
                a1 = s * W_hh1[row * HID + kd];
                a2 = s * W_ih2[row * HID + kd];
            } else if (kd == HID) {           // bias slot (B[15][n] == 1.0)
                a1 = s * (b_ih1[row] + b_hh1[row]);
                a2 = s * (b_ih2[row] + b_hh2[row]);
            } else if (kd >= 16 && kd - 16 < HID) {
                a2 = s * W_hh2[row * HID + (kd - 16)];   // h2 half of fused L2
            }
            A1[gi][j] = (_Float16)a1;
            A2[gi][j] = (_Float16)a2;
        }
    }

    float wihx[4];
    #pragma unroll
    for (int gi = 0; gi < 4; ++gi)
        wihx[gi] = m * sA[gi] * W_ih1[gi * HID + kk];
    const float wl   = m * W_lin[kk];
    const float blin = b_lin[0];

    // B-build transpose: dest lane (q,n) pair r <- src lane n*16 + (q&1)*8 + 2r
    const int ab0 = 4 * ((lane & 15) * 16 + ((lane >> 4) & 1) * 8);
    const int ab1 = ab0 + 8;
    const int ab2 = ab0 + 16;
    const int ab3 = ab0 + 24;
    // D-redist: dest lane (g,k) <- src lane (k>>2)*16 + g, reg k&3
    const int adD = 4 * (((lane & 15) >> 2) * 16 + (lane >> 4));
    const bool k1   = (k & 1) != 0;
    const bool k2   = (k & 2) != 0;
    const bool qlow = (g < 2);                         // h1-half of B
    const int  mskb = (g == 1) ? 0x3C000000 : 0;       // f16 1.0 -> B[15] slot

    // packed fp16 pair {h[k], h[k+1]} per lane (R8-verified construction)
    auto packh = [&](float h) -> int {
        const _Float16 hh = (_Float16)h;
        const int lo = (int)(unsigned short)__builtin_bit_cast(unsigned short, hh);
        const int hi = dppi<0x101>(lo);
        const v2h pr = {__builtin_bit_cast(_Float16, (unsigned short)lo),
                        __builtin_bit_cast(_Float16, (unsigned short)(hi & 0xFFFF))};
        return __builtin_bit_cast(int, pr);
    };

    auto buildB2 = [&](int pk1, int pk2) -> v8h {       // [h1 ; 1 ; h2 ; 0]
        const int t0a = bperm(ab0, pk1), t0b = bperm(ab0, pk2);
        const int t1a = bperm(ab1, pk1), t1b = bperm(ab1, pk2);
        const int t2a = bperm(ab2, pk1), t2b = bperm(ab2, pk2);
        const int t3a = bperm(ab3, pk1), t3b = bperm(ab3, pk2);
        v4i r;
        r[0] = qlow ? t0a : t0b;
        r[1] = qlow ? t1a : t1b;
        r[2] = qlow ? t2a : t2b;
        r[3] = (qlow ? t3a : t3b) | mskb;
        return __builtin_bit_cast(v8h, r);
    };
    auto deriveB1 = [&](v8h b2) -> v8h {                // keep h1-half, zero rest
        v4i r = __builtin_bit_cast(v4i, b2);
        r[0] = qlow ? r[0] : 0;
        r[1] = qlow ? r[1] : 0;
        r[2] = qlow ? r[2] : 0;
        r[3] = qlow ? r[3] : 0;
        return __builtin_bit_cast(v8h, r);
    };
    auto redist = [&](v4f D) -> float {
        const int t0 = bperm(adD, __float_as_int(D[0]));
        const int t1 = bperm(adD, __float_as_int(D[1]));
        const int t2 = bperm(adD, __float_as_int(D[2]));
        const int t3 = bperm(adD, __float_as_int(D[3]));
        const int s01 = k1 ? t1 : t0;
        const int s23 = k1 ? t3 : t2;
        return __int_as_float(k2 ? s23 : s01);
    };

    v4i binit = {0, 0, 0, mskb};
    v8h B1cur = __builtin_bit_cast(v8h, binit);   // h1(-1)=0, bias slot live
    int pk2 = 0;                                  // h2(-1)=0
    float c1 = 0.0f, c2 = 0.0f, outv = 0.0f;
    const v4f z4 = {0.0f, 0.0f, 0.0f, 0.0f};

    auto step = [&](auto Sc, auto UseOvC, float xbpre, float& oreg) {
        constexpr int  S      = decltype(Sc)::v;
        constexpr bool USE_OV = decltype(UseOvC)::v;

        // ---- L1 gates on MFMA pipe (h1(t-1) + bias) ----
        const v4f D0 = mfma16x32(A1[0], B1cur, z4);
        const v4f D1 = mfma16x32(A1[1], B1cur, z4);
        const v4f D2 = mfma16x32(A1[2], B1cur, z4);
        const v4f D3 = mfma16x32(A1[3], B1cur, z4);
        const float xb = USE_OV ? outv : xbpre;
        const float a0 = __builtin_fmaf(wihx[0], xb, redist(D0));
        const float a1 = __builtin_fmaf(wihx[1], xb, redist(D1));
        const float a2 = __builtin_fmaf(wihx[2], xb, redist(D2));
        const float a3 = __builtin_fmaf(wihx[3], xb, redist(D3));

        const float ig = rcp_(1.0f + exp2_(a0));
        const float fg = rcp_(1.0f + exp2_(a1));
        const float gg = __builtin_fmaf(2.0f, rcp_(1.0f + exp2_(a2)), -1.0f);
        const float og = rcp_(1.0f + exp2_(a3));
        c1 = __builtin_fmaf(fg, c1, ig * gg);
        const float h1n = og * tanh_(c1);

        // ---- L2 fused gates: [W2i|bias|W2h] . [h1(t);1;h2(t-1)] ----
        const int pk1 = packh(h1n);
        const v8h B2  = buildB2(pk1, pk2);
        const v4f E0 = mfma16x32(A2[0], B2, z4);
        const v4f E1 = mfma16x32(A2[1], B2, z4);
        const v4f E2 = mfma16x32(A2[2], B2, z4);
        const v4f E3 = mfma16x32(A2[3], B2, z4);
        const float d0 = redist(E0);
        const float d1 = redist(E1);
        const float d2 = redist(E2);
        const float d3 = redist(E3);

        const float i2 = rcp_(1.0f + exp2_(d0));
        const float f2 = rcp_(1.0f + exp2_(d1));
        const float g2 = __builtin_fmaf(2.0f, rcp_(1.0f + exp2_(d2)), -1.0f);
        const float o2 = rcp_(1.0f + exp2_(d3));
        c2 = __builtin_fmaf(f2, c2, i2 * g2);
        const float h2n = o2 * tanh_(c2);
        pk2 = packh(h2n);
        B1cur = deriveB1(B2);          // h1(t) half -> next step's L1 operand

        // ---- out = <W_lin, h2> + b (DPP row reduce); keep own time slot ----
        const float ov = row_sum_bcast(wl * h2n) + blin;
        oreg = (k == S) ? ov : oreg;
        outv = ov;
    };

    const size_t inb  = (size_t)(b0 + g) * TMAIN + k;
    const size_t outb = (size_t)(b0 + g) * OUTW  + k;

    // ---- main: 64 chunks of 16 steps; x held in-register, prefetched ----
    float xnext = input[inb];
    #pragma unroll 1
    for (int ch = 0; ch < TMAIN / 16; ++ch) {
        const float xcur = xnext;
        const int tn = (ch < TMAIN / 16 - 1) ? (ch + 1) * 16 : ch * 16;
        xnext = input[inb + tn];
        float oreg = 0.0f;
        unroll_for<0, 16>([&](auto sc) {
            constexpr int s = decltype(sc)::v;
            step(sc, ic<0>{}, dppf<0x150 + s>(xcur), oreg);
        });
        out[outb + ch * 16] = oreg;
    }

    // ---- future: x = previous out (row-uniform outv) ----
    #pragma unroll 1
    for (int ch = 0; ch < FUT / 16; ++ch) {
        float oreg = 0.0f;
        unroll_for<0, 16>([&](auto sc) {
            step(sc, ic<1>{}, 0.0f, oreg);
        });
        out[outb + TMAIN + ch * 16] = oreg;
    }
}

extern "C" void kernel_launch(void* const* d_in, const int* in_sizes, int n_in,
                              void* d_out, int out_size, void* d_ws, size_t ws_size,
                              hipStream_t stream)
{
    const float* input = (const float*)d_in[0];
    const float* W_ih1 = (const float*)d_in[1];
    const float* W_hh1 = (const float*)d_in[2];
    const float* b_ih1 = (const float*)d_in[3];
    const float* b_hh1 = (const float*)d_in[4];
    const float* W_ih2 = (const float*)d_in[5];
    const float* W_hh2 = (const float*)d_in[6];
    const float* b_ih2 = (const float*)d_in[7];
    const float* b_hh2 = (const float*)d_in[8];
    const float* W_lin = (const float*)d_in[9];
    const float* b_lin = (const float*)d_in[10];
    // d_in[11] = future (=64), compiled in as FUT

    // 4096 batches / (4 per wave * 4 waves per block) = 256 blocks
    lstm_seq_kernel<<<256, 256, 0, stream>>>(
        input, W_ih1, W_hh1, b_ih1, b_hh1,
        W_ih2, W_hh2, b_ih2, b_hh2, W_lin, b_lin,
        (float*)d_out);
}

// Round 12
// 476.209 us; speedup vs baseline: 1.4978x; 1.4978x over previous
//
#include <hip/hip_runtime.h>

#define HID   15
#define TMAIN 1024
#define FUT   64
#define OUTW  (TMAIN + FUT)   // 1088

typedef _Float16 v2h __attribute__((ext_vector_type(2)));

__device__ __forceinline__ float rcp_(float x)  { return __builtin_amdgcn_rcpf(x); }
__device__ __forceinline__ float exp2_(float x) { return __builtin_amdgcn_exp2f(x); }

template<int I> struct ic { static constexpr int v = I; };
template<int J, int N, class F>
__device__ __forceinline__ void unroll_for(F&& f) {
    if constexpr (J < N) { f(ic<J>{}); unroll_for<J + 1, N>(f); }
}

// DPP ctrl: 0x150+j = row_newbcast:j (CDNA), 0x110+n = row_shr:n, 0x101 = row_shl:1
template<int CTRL>
__device__ __forceinline__ int dppi(int x) {
    return __builtin_amdgcn_update_dpp(0, x, CTRL, 0xF, 0xF, true);
}
template<int CTRL>
__device__ __forceinline__ float dppf(float x) {
    return __int_as_float(dppi<CTRL>(__float_as_int(x)));
}
__device__ __forceinline__ float row_sum_bcast(float p) {
    p += dppf<0x111>(p);
    p += dppf<0x112>(p);
    p += dppf<0x114>(p);
    p += dppf<0x118>(p);
    return dppf<0x15F>(p);
}
__device__ __forceinline__ float fdot2(v2h a, v2h b, float c) {
    return __builtin_amdgcn_fdot2(a, b, c, false);
}
__device__ __forceinline__ v2h pkrtz(float lo, float hi) {
    return __builtin_bit_cast(v2h, __builtin_amdgcn_cvt_pkrtz(lo, hi));
}

// R12 = R10 (best: 471 us) + shared-rcp activations + dependency reorder.
// R11 lesson (MFMA offload): D-layout->act-layout marshaling needs cross-quad
// moves = LDS pipe (bperm/swizzle); serial recurrence at 1 wave/SIMD cannot
// hide LDS latency -> net loss (713 us, VALUBusy 44%). VALU formulation stays.
// Shared rcp: sigma(a)=rcp(1+e); for a gate pair, r=rcp(t0*t1) gives
// sigma0=t1*r, sigma1=t0*r (tanh_g = 2*t_o*r - 1). 2 rcp saved per layer ->
// 20 -> 16 trans ops/step (model: trans ~16cyc/wave64 is the #2 consumer
// after the 384-cyc dot2 block). Preacts |a|<~6 -> e<=2^9: no overflow risk.
// Reorder: pair-7 fix + packh(h2) issued before the out-reduce chain in main
// phase (next step's L1/L2 depend on hb1/hpk2, not on the 5-DPP reduce).
__global__ __launch_bounds__(256)
__attribute__((amdgpu_waves_per_eu(1, 1)))
void lstm_seq_kernel(const float* __restrict__ input,
                     const float* __restrict__ W_ih1, const float* __restrict__ W_hh1,
                     const float* __restrict__ b_ih1, const float* __restrict__ b_hh1,
                     const float* __restrict__ W_ih2, const float* __restrict__ W_hh2,
                     const float* __restrict__ b_ih2, const float* __restrict__ b_hh2,
                     const float* __restrict__ W_lin, const float* __restrict__ b_lin,
                     float* __restrict__ out)
{
    const int tid  = threadIdx.x;
    const int wq   = tid >> 6;
    const int lane = tid & 63;
    const int g    = lane >> 4;       // batch subgroup == DPP row
    const int k    = lane & 15;       // hidden unit / time-slot (15 = pad unit)
    const int b0   = (blockIdx.x * 4 + wq) * 4;

    const bool pad = (k >= HID);
    const float m  = pad ? 0.0f : 1.0f;
    const int  kk  = pad ? 0 : k;

    const float L2E = 1.442695040888963f;
    const float sA[4] = {-L2E, -L2E, -2.0f * L2E, -L2E};  // i,f sigm; g tanh; o sigm

    // packed fp16 weight pairs; pair 7 of w1 carries the x weight in .y
    v2h w1[4][8], w2i[4][8], w2h[4][8];
    float bb1[4], bb2[4];
    #pragma unroll
    for (int gi = 0; gi < 4; ++gi) {
        const int row = gi * HID + kk;
        const float s = m * sA[gi];
        bb1[gi] = s * (b_ih1[row] + b_hh1[row]);
        bb2[gi] = s * (b_ih2[row] + b_hh2[row]);
        #pragma unroll
        for (int j = 0; j < 8; ++j) {
            const int c0 = 2 * j, c1i = 2 * j + 1;
            w1 [gi][j] = (v2h){(_Float16)(s * W_hh1[row * HID + c0]),
                               (_Float16)((c1i < HID) ? s * W_hh1[row * HID + c1i]
                                                      : s * W_ih1[row])};   // x slot
            w2i[gi][j] = (v2h){(_Float16)(s * W_ih2[row * HID + c0]),
                               (_Float16)((c1i < HID) ? s * W_ih2[row * HID + c1i] : 0.0f)};
            w2h[gi][j] = (v2h){(_Float16)(s * W_hh2[row * HID + c0]),
                               (_Float16)((c1i < HID) ? s * W_hh2[row * HID + c1i] : 0.0f)};
        }
    }
    const float wl   = m * W_lin[kk];
    const float blin = b_lin[0];

    // lane k -> packed pair {h16[k], h16[k+1]} (lane15 edge -> 0 via bound_ctrl)
    auto packh = [&](float h) -> int {
        const _Float16 hh = (_Float16)h;                   // RNE
        const int lo = (int)(unsigned short)__builtin_bit_cast(unsigned short, hh);
        const int hi = dppi<0x101>(lo);
        const v2h pr = {__builtin_bit_cast(_Float16, (unsigned short)lo),
                        __builtin_bit_cast(_Float16, (unsigned short)(hi & 0xFFFF))};
        return __builtin_bit_cast(int, pr);
    };

    v2h hb1[8];                        // h1 broadcast pairs (persist across steps)
    #pragma unroll
    for (int j = 0; j < 8; ++j) hb1[j] = (v2h){(_Float16)0.0f, (_Float16)0.0f};
    int hpk2 = 0;                      // packed h2 = {0,0}
    float c1 = 0.0f, c2 = 0.0f, outv = 0.0f;

    auto step = [&](auto Sc, auto UseOvC, float xvpre, float& oreg) {
        constexpr int  S      = decltype(Sc)::v;
        constexpr bool USE_OV = decltype(UseOvC)::v;

        // ---- layer-1 pre-acts from persisted hb1 (pair7.y carries x(t)) ----
        float a0 = bb1[0], a1 = bb1[1], a2 = bb1[2], a3 = bb1[3];
        unroll_for<0, 8>([&](auto jc) {
            constexpr int j = decltype(jc)::v;
            a0 = fdot2(w1[0][j], hb1[j], a0);
            a1 = fdot2(w1[1][j], hb1[j], a1);
            a2 = fdot2(w1[2][j], hb1[j], a2);
            a3 = fdot2(w1[3][j], hb1[j], a3);
        });

        // ---- layer-2 hh part (prev h2; fills L1-act latency) ----
        float d0 = bb2[0], d1 = bb2[1], d2 = bb2[2], d3 = bb2[3];
        unroll_for<0, 8>([&](auto jc) {
            constexpr int j = decltype(jc)::v;
            const v2h hb = __builtin_bit_cast(v2h, dppi<0x150 + 2*j>(hpk2));
            d0 = fdot2(w2h[0][j], hb, d0);
            d1 = fdot2(w2h[1][j], hb, d1);
            d2 = fdot2(w2h[2][j], hb, d2);
            d3 = fdot2(w2h[3][j], hb, d3);
        });

        // ---- layer-1 activations (shared rcp), c1, h1 ----
        {
            const float t0 = 1.0f + exp2_(a0);       // i (sigm)
            const float t1 = 1.0f + exp2_(a1);       // f (sigm)
            const float t2 = 1.0f + exp2_(a2);       // g (tanh, scale folded)
            const float t3 = 1.0f + exp2_(a3);       // o (sigm)
            const float r01 = rcp_(t0 * t1);
            const float r23 = rcp_(t2 * t3);
            const float ig = t1 * r01;
            const float fg = t0 * r01;
            const float gg = __builtin_fmaf(2.0f, t3 * r23, -1.0f);
            const float og = t2 * r23;
            c1 = __builtin_fmaf(fg, c1, ig * gg);
            const float ec = exp2_(c1 * (-2.0f * L2E));
            const float th = __builtin_fmaf(2.0f, rcp_(1.0f + ec), -1.0f);
            const float h1n = og * th;

            // ---- build hb1 once (L2-ih now; L1-hh next step) ----
            const int hpk1 = packh(h1n);
            unroll_for<0, 8>([&](auto jc) {
                constexpr int j = decltype(jc)::v;
                hb1[j] = __builtin_bit_cast(v2h, dppi<0x150 + 2*j>(hpk1));
            });
            // pair-7 fix (main phase): {h1[14], x(t+1)} ready before out-reduce
            if constexpr (!USE_OV)
                hb1[7] = pkrtz(dppf<0x15E>(h1n), xvpre);
            else
                (void)xvpre;
            unroll_for<0, 8>([&](auto jc) {
                constexpr int j = decltype(jc)::v;
                d0 = fdot2(w2i[0][j], hb1[j], d0);
                d1 = fdot2(w2i[1][j], hb1[j], d1);
                d2 = fdot2(w2i[2][j], hb1[j], d2);
                d3 = fdot2(w2i[3][j], hb1[j], d3);
            });
            if constexpr (USE_OV) {
                // restore h1-only pair7 for now; xv patched after ov is known
                hb1[7] = pkrtz(dppf<0x15E>(h1n), 0.0f);
            }
        }

        // ---- layer-2 activations (shared rcp), c2, h2 ----
        const float t0 = 1.0f + exp2_(d0);
        const float t1 = 1.0f + exp2_(d1);
        const float t2 = 1.0f + exp2_(d2);
        const float t3 = 1.0f + exp2_(d3);
        const float r01 = rcp_(t0 * t1);
        const float r23 = rcp_(t2 * t3);
        const float i2 = t1 * r01;
        const float f2 = t0 * r01;
        const float g2 = __builtin_fmaf(2.0f, t3 * r23, -1.0f);
        const float o2 = t2 * r23;
        c2 = __builtin_fmaf(f2, c2, i2 * g2);
        const float ec = exp2_(c2 * (-2.0f * L2E));
        const float th = __builtin_fmaf(2.0f, rcp_(1.0f + ec), -1.0f);
        const float h2n = o2 * th;
        hpk2 = packh(h2n);             // before the reduce: next L2-hh unblocked

        // ---- out = <W_lin, h2> + b; keep own time slot ----
        const float ov = row_sum_bcast(wl * h2n) + blin;
        oreg = (k == S) ? ov : oreg;

        if constexpr (USE_OV) {
            // future phase: x(t+1) = ov -> patch pair7.y now
            const v2h p7 = hb1[7];
            hb1[7] = (v2h){p7.x, (_Float16)ov};
        }
        outv = ov;
    };

    const size_t inb  = (size_t)(b0 + g) * TMAIN + k;
    const size_t outb = (size_t)(b0 + g) * OUTW  + k;

    float xcur = input[inb];
    // prologue: x(0) into pair7.y
    hb1[7] = pkrtz(0.0f, dppf<0x150>(xcur));

    // ---- main: 64 chunks of 16 steps; x prefetched one chunk ahead ----
    #pragma unroll 1
    for (int ch = 0; ch < TMAIN / 16; ++ch) {
        const bool last = (ch == TMAIN / 16 - 1);
        const float xnext = input[inb + (last ? ch : ch + 1) * 16];
        float oreg = 0.0f;
        unroll_for<0, 16>([&](auto sc) {
            constexpr int s = decltype(sc)::v;
            if constexpr (s < 15) {
                step(sc, ic<0>{}, dppf<0x150 + s + 1>(xcur), oreg);
            } else {
                if (last) step(sc, ic<1>{}, 0.0f, oreg);
                else      step(sc, ic<0>{}, dppf<0x150>(xnext), oreg);
            }
        });
        out[outb + ch * 16] = oreg;
        xcur = xnext;
    }

    // ---- future: x = previous out (USE_OV patches pair7.y with ov) ----
    #pragma unroll 1
    for (int ch = 0; ch < FUT / 16; ++ch) {
        float oreg = 0.0f;
        unroll_for<0, 16>([&](auto sc) {
            step(sc, ic<1>{}, 0.0f, oreg);
        });
        out[outb + TMAIN + ch * 16] = oreg;
    }
}

extern "C" void kernel_launch(void* const* d_in, const int* in_sizes, int n_in,
                              void* d_out, int out_size, void* d_ws, size_t ws_size,
                              hipStream_t stream)
{
    const float* input = (const float*)d_in[0];
    const float* W_ih1 = (const float*)d_in[1];
    const float* W_hh1 = (const float*)d_in[2];
    const float* b_ih1 = (const float*)d_in[3];
    const float* b_hh1 = (const float*)d_in[4];
    const float* W_ih2 = (const float*)d_in[5];
    const float* W_hh2 = (const float*)d_in[6];
    const float* b_ih2 = (const float*)d_in[7];
    const float* b_hh2 = (const float*)d_in[8];
    const float* W_lin = (const float*)d_in[9];
    const float* b_lin = (const float*)d_in[10];
    // d_in[11] = future (=64), compiled in as FUT

    // 4096 batches / (4 per wave * 4 waves per block) = 256 blocks
    lstm_seq_kernel<<<256, 256, 0, stream>>>(
        input, W_ih1, W_hh1, b_ih1, b_hh1,
        W_ih2, W_hh2, b_ih2, b_hh2, W_lin, b_lin,
        (float*)d_out);
}